// Round 2
// baseline (370.562 us; speedup 1.0000x reference)
//
#include <hip/hip_runtime.h>

typedef __bf16 bf16_t;
typedef __bf16 bf16x4 __attribute__((ext_vector_type(4)));
typedef __bf16 bf16x8 __attribute__((ext_vector_type(8)));
typedef float f32x4 __attribute__((ext_vector_type(4)));

#define MFMA16(a, b, c) __builtin_amdgcn_mfma_f32_16x16x32_bf16((a), (b), (c), 0, 0, 0)

// ---------------------------------------------------------------------------
// Swizzled 64-col bf16 tile helpers (stage + frag-read sides use same swizzle).
// ---------------------------------------------------------------------------
__device__ __forceinline__ const bf16_t* tile_ptr(const bf16_t* t, int row, int kchunk) {
    return t + row * 64 + (((kchunk ^ (row & 7))) << 3);
}

__device__ __forceinline__ void stage64(const bf16_t* __restrict__ gbase, size_t gstride,
                                        bf16_t* lds_rowbase, int lane) {
    const int rr = lane >> 3, cl = lane & 7;
    const bf16_t* g = gbase + (size_t)rr * gstride + ((cl ^ rr) << 3);
    __builtin_amdgcn_global_load_lds((__attribute__((address_space(1))) const void*)g,
                                     (__attribute__((address_space(3))) void*)lds_rowbase,
                                     16, 0, 0);
}

// ---------------------------------------------------------------------------
// Kernel 0: fp32 -> bf16 conversion pre-pass.
// ---------------------------------------------------------------------------
__global__ void __launch_bounds__(256) k_cvt(
    const float* __restrict__ q, const float* __restrict__ wi, const float* __restrict__ wo,
    bf16_t* __restrict__ qb, bf16_t* __restrict__ wib, bf16_t* __restrict__ wob)
{
    const int g = blockIdx.x * 256 + threadIdx.x;
    const float* src; bf16_t* dst; int off;
    if (g < 1048576)      { src = q;  dst = qb;  off = g; }
    else if (g < 1441792) { src = wi; dst = wib; off = g - 1048576; }
    else                  { src = wo; dst = wob; off = g - 1441792; }
    const float4* s4 = (const float4*)(src + (size_t)off * 8);
    float4 a = s4[0], b = s4[1];
    bf16x8 v;
    v[0] = (bf16_t)a.x; v[1] = (bf16_t)a.y; v[2] = (bf16_t)a.z; v[3] = (bf16_t)a.w;
    v[4] = (bf16_t)b.x; v[5] = (bf16_t)b.y; v[6] = (bf16_t)b.z; v[7] = (bf16_t)b.w;
    *(bf16x8*)(dst + (size_t)off * 8) = v;
}

// ---------------------------------------------------------------------------
// Kernel 1: QKV projection — 256x256-tile, 8-wave, 8-phase pipelined schedule
// with COUNTED vmcnt (T4). Staging for tile t+1: first-4 at the t-1/t boundary
// (into the buffer freed at that barrier), last-4 at t.p1. Boundary wait is
// s_waitcnt vmcnt(4): all of t+1 complete, t+2's first-4 stay in flight
// across the barrier. vmcnt(0) only in the tail (t>=14) where no younger
// loads exist.
//   Qh/Kh: [head][si][d]  (Q scaled by (1/8)*log2(e) -- exp2 fold)
//   Vt:    [head][si>>3][d][si&7]
// ---------------------------------------------------------------------------
__global__ void __launch_bounds__(512, 2) k_qkv(
    const bf16_t* __restrict__ A, const bf16_t* __restrict__ W,
    const float* __restrict__ bias,
    bf16_t* __restrict__ Qh, bf16_t* __restrict__ Kh, bf16_t* __restrict__ Vt)
{
    __shared__ bf16_t smem[65536];          // 128 KiB: [As0|Bs0|As1|Bs1]; Cs in epilogue
    bf16_t* const As0 = smem;
    bf16_t* const Bs0 = smem + 16384;
    bf16_t* const As1 = smem + 32768;
    bf16_t* const Bs1 = smem + 49152;

    // XCD-chunked bijective swizzle (384 blocks, 48/XCD); n fastest inside a
    // chunk so the 12 blocks sharing an A m-panel land on one XCD's L2.
    const int bid = blockIdx.x;
    const int swz = (bid & 7) * 48 + (bid >> 3);
    const int mblk = swz / 12, nblk = swz - mblk * 12;
    const int m0 = mblk * 256;
    const int n0 = nblk * 256;              // permuted n' space
    const int which = n0 >> 10;             // 0=Q, 1=K, 2=V (block-uniform)
    const int hb0 = (n0 & 1023) >> 6;       // first of 4 head-units in this tile
    const int t = threadIdx.x;
    const int wid = t >> 6, lane = t & 63;
    const int quad = lane >> 4, l16 = lane & 15;
    const int wm = (wid >> 2) * 128, wn = (wid & 3) * 64;   // wave tile 128x64

    f32x4 acc[8][4] = {};

    auto stA = [&](bf16_t* dst, int kt, int p) {
        const int rb = wid * 32 + p * 8;
        stage64(A + (size_t)(m0 + rb) * 1024 + kt * 64, 1024, dst + rb * 64, lane);
    };
    auto stB = [&](bf16_t* dst, int kt, int p) {
        const int rb = wid * 32 + p * 8;
        const int np = n0 + rb;
        const int wrow = ((np & 1023) >> 6) * 192 + which * 64 + (np & 63);
        stage64(W + (size_t)wrow * 1024 + kt * 64, 1024, dst + rb * 64, lane);
    };

#define FENCE()    asm volatile("" ::: "memory")
#define BAR()      do { FENCE(); __builtin_amdgcn_s_barrier(); FENCE(); } while (0)
#define WAIT_LDS() asm volatile("s_waitcnt lgkmcnt(0)" ::: "memory")
#define WAIT_VM4() asm volatile("s_waitcnt vmcnt(4)" ::: "memory")
#define WAIT_VM0() asm volatile("s_waitcnt vmcnt(0)" ::: "memory")

#define LOAD_AF(BUF, KS) { _Pragma("unroll") for (int i = 0; i < 8; ++i) \
        af[i] = *(const bf16x8*)tile_ptr((BUF), wm + i * 16 + l16, (KS) * 4 + quad); }
#define LOAD_B(BUF, J0, KS) { \
        b0 = *(const bf16x8*)tile_ptr((BUF), wn + (J0) * 16 + l16, (KS) * 4 + quad); \
        b1 = *(const bf16x8*)tile_ptr((BUF), wn + (J0) * 16 + 16 + l16, (KS) * 4 + quad); }
#define MM16(J0) { __builtin_amdgcn_s_setprio(1); \
        _Pragma("unroll") for (int i = 0; i < 8; ++i) { \
            acc[i][J0] = MFMA16(af[i], b0, acc[i][J0]); \
            acc[i][(J0) + 1] = MFMA16(af[i], b1, acc[i][(J0) + 1]); } \
        __builtin_amdgcn_s_setprio(0); }

    // One K-tile (BK=64) = 4 phases of 16 MFMA, consuming CA/CB.
    // OA/OB = other buffer (tile tt+1 lands there).
    auto ktile = [&](bf16_t* CA, bf16_t* CB, bf16_t* OA, bf16_t* OB, int tt) {
        bf16x8 af[8], b0, b1;
        // ---- phase 1: ds af(ks0)+b01(ks0); issue last-4 of tile tt+1 ----
        LOAD_AF(CA, 0); LOAD_B(CB, 0, 0);
        if (tt < 15) { stA(OA, tt + 1, 2); stB(OB, tt + 1, 2);
                       stA(OA, tt + 1, 3); stB(OB, tt + 1, 3); }
        BAR(); WAIT_LDS(); MM16(0); BAR();
        // ---- phase 2: ds b23(ks0) ----
        LOAD_B(CB, 2, 0);
        BAR(); WAIT_LDS(); MM16(2); BAR();
        // ---- phase 3: ds af(ks1)+b01(ks1) ----
        LOAD_AF(CA, 1); LOAD_B(CB, 0, 1);
        BAR(); WAIT_LDS(); MM16(0); BAR();
        // ---- phase 4: ds b23(ks1) ----
        LOAD_B(CB, 2, 1);
        BAR(); WAIT_LDS(); MM16(2); BAR();
        // ---- boundary: CA/CB now dead (all reads completed before the end
        // barrier). Issue first-4 of tile tt+2 into them, counted wait. ----
        if (tt < 14) {
            stA(CA, tt + 2, 0); stB(CB, tt + 2, 0);
            stA(CA, tt + 2, 1); stB(CB, tt + 2, 1);
            WAIT_VM4();                     // all of tile tt+1 landed; 4 in flight
        } else {
            WAIT_VM0();                     // tail: no younger loads to count
        }
        BAR();
    };

    // Prologue: all 8 of tile 0 -> buf0, first-4 of tile 1 -> buf1.
    #pragma unroll
    for (int p = 0; p < 4; ++p) { stA(As0, 0, p); stB(Bs0, 0, p); }
    stA(As1, 1, 0); stB(Bs1, 1, 0); stA(As1, 1, 1); stB(Bs1, 1, 1);
    WAIT_VM4(); BAR();

    #pragma unroll 1
    for (int it = 0; it < 8; ++it) {
        ktile(As0, Bs0, As1, Bs1, 2 * it);
        ktile(As1, Bs1, As0, Bs0, 2 * it + 1);
    }

    // ---- Epilogue phase 1: C tile (bias+scale applied) -> swizzled LDS ----
    // All staging quiesced by the t=14/15 vmcnt(0) waits; smem reused as Cs[256][256].
    const float scalev = (which == 0) ? 0.180336880111112f : 1.0f;  // 1/8 * log2(e)
    #pragma unroll
    for (int j = 0; j < 4; ++j) {
        const int nl = wn + j * 16 + l16;
        const float bv = bias[(hb0 + (nl >> 6)) * 192 + which * 64 + (nl & 63)];
        #pragma unroll
        for (int i = 0; i < 8; ++i) {
            #pragma unroll
            for (int rg = 0; rg < 4; ++rg) {
                const int ml = wm + i * 16 + quad * 4 + rg;
                smem[ml * 256 + (((nl >> 3) ^ ((ml >> 3) & 7)) << 3) + (nl & 7)] =
                    (bf16_t)((acc[i][j][rg] + bv) * scalev);
            }
        }
    }
    __syncthreads();

    // ---- Epilogue phase 2: coalesced stores (8 waves) ----
    const int si0 = m0 >> 3;
    if (which < 2) {
        bf16_t* dst = which ? Kh : Qh;
        #pragma unroll
        for (int u = 0; u < 4; ++u) {
            const int unit = wid * 4 + u;           // (h, bi), 32 units
            const int h = unit >> 3, bi = unit & 7;
            const int head = bi * 16 + hb0 + h;
            #pragma unroll
            for (int pass = 0; pass < 4; ++pass) {
                const int si = pass * 8 + (lane >> 3);
                const int dc = lane & 7;
                const int ml = si * 8 + bi;
                const int nch = (h * 8 + dc) ^ (si & 7);
                bf16x8 v = *(const bf16x8*)&smem[ml * 256 + nch * 8];
                *(bf16x8*)(dst + (size_t)head * 65536 + (size_t)(si0 + si) * 64 + dc * 8) = v;
            }
        }
    } else {
        #pragma unroll
        for (int u = 0; u < 16; ++u) {
            const int unit = wid * 16 + u;          // (h, bi, c), 128 units
            const int h = unit >> 5, bi = (unit >> 2) & 7, c = unit & 3;
            const int head = bi * 16 + hb0 + h;
            const int d = lane;
            bf16x8 v;
            #pragma unroll
            for (int e = 0; e < 8; ++e) {
                const int ml = (c * 8 + e) * 8 + bi;
                const int nch = (h * 8 + (d >> 3)) ^ e;
                v[e] = smem[ml * 256 + nch * 8 + (d & 7)];
            }
            *(bf16x8*)(Vt + (size_t)head * 65536 +
                       (size_t)(si0 / 8 + c) * 512 + (size_t)d * 8) = v;
        }
    }
#undef FENCE
#undef BAR
#undef WAIT_LDS
#undef WAIT_VM4
#undef WAIT_VM0
#undef LOAD_AF
#undef LOAD_B
#undef MM16
}

// ---------------------------------------------------------------------------
// Kernel 2: fused attention. Block = (head, 128-row q-tile); wave owns 32
// q-rows. S^T computed via MFMA(K,Q) so P-writes are b64 (4 consecutive keys
// per lane). Q frags straight from global; ones-column frag synthesized in
// regs. XCD-affine block swizzle: a head's 8 q-tiles share one XCD's L2.
// ---------------------------------------------------------------------------
__global__ void __launch_bounds__(256, 4) k_attn(
    const bf16_t* __restrict__ Qh, const bf16_t* __restrict__ Kh,
    const bf16_t* __restrict__ Vg, bf16_t* __restrict__ Ctx)
{
    __shared__ bf16_t Ks[64 * 64];
    __shared__ bf16_t Vts[64 * 64];     // V^T tile (rows=d, cols=key), XOR-swizzled
    __shared__ bf16_t Pw[4][32 * 64];   // per-wave P [qrow][key], XOR-swizzled

    const int bid = blockIdx.x;
    const int head = (bid & 7) * 16 + ((bid >> 3) & 15);  // bid%8 = XCD (heuristic)
    const int qt = bid >> 7;
    const int t = threadIdx.x;
    const int wave = t >> 6, lane = t & 63;
    const int quad = lane >> 4, l16 = lane & 15;

    const bf16_t* Qg = Qh + (size_t)head * 65536 + (size_t)qt * 8192;
    const bf16_t* Kg = Kh + (size_t)head * 65536;
    const bf16_t* Vgh = Vg + (size_t)head * 65536;   // [sc][d][s7]

    // Q b-frags from global: lane l16 = q-row, 16B contiguous per lane
    bf16x8 qf[2][2];
    #pragma unroll
    for (int half = 0; half < 2; ++half)
        #pragma unroll
        for (int ks = 0; ks < 2; ++ks)
            qf[half][ks] = *(const bf16x8*)(
                Qg + (size_t)(wave * 32 + half * 16 + l16) * 64 + ks * 32 + quad * 8);

    // ones-column B-frag: column 64 of [V | 1 | 0] augmentation -> l16==0 lanes
    bf16x8 ones;
    #pragma unroll
    for (int e = 0; e < 8; ++e) ones[e] = (bf16_t)((l16 == 0) ? 1.0f : 0.0f);

    f32x4 vacc[2][5] = {};

    for (int kt = 0; kt < 16; ++kt) {
        __syncthreads();
        #pragma unroll
        for (int p = 0; p < 2; ++p) {
            const int rb = wave * 16 + p * 8;
            stage64(Kg + (size_t)(kt * 64 + rb) * 64, 64, Ks + rb * 64, lane);
            {   // V^T staging from [sc][d][s7]
                const int rr = lane >> 3, cl = lane & 7;
                const bf16_t* g = Vgh + (size_t)(kt * 8 + (cl ^ rr)) * 512
                                      + (size_t)(rb + rr) * 8;
                __builtin_amdgcn_global_load_lds(
                    (__attribute__((address_space(1))) const void*)g,
                    (__attribute__((address_space(3))) void*)(Vts + rb * 64), 16, 0, 0);
            }
        }
        __syncthreads();

        // S^T = K Q^T : D[key][qrow]; lane holds keys quad*4+rg (consecutive!)
        f32x4 s[2][4] = {};
        #pragma unroll
        for (int ks = 0; ks < 2; ++ks) {
            #pragma unroll
            for (int j = 0; j < 4; ++j) {
                bf16x8 kf = *(const bf16x8*)tile_ptr(Ks, j * 16 + l16, ks * 4 + quad);
                s[0][j] = MFMA16(kf, qf[0][ks], s[0][j]);
                s[1][j] = MFMA16(kf, qf[1][ks], s[1][j]);
            }
        }

        // P = exp2(S) -> Pw[qrow][key], 4 consecutive keys per lane = b64 write
        #pragma unroll
        for (int half = 0; half < 2; ++half) {
            const int row = half * 16 + l16;
            #pragma unroll
            for (int j = 0; j < 4; ++j) {
                bf16x4 pv;
                #pragma unroll
                for (int rg = 0; rg < 4; ++rg)
                    pv[rg] = (bf16_t)exp2f(s[half][j][rg]);
                const int chunk = j * 2 + (quad >> 1);
                *(bf16x4*)&Pw[wave][row * 64 + ((chunk ^ (row & 7)) << 3) + (quad & 1) * 4] = pv;
            }
        }
        asm volatile("s_waitcnt lgkmcnt(0)" ::: "memory");  // wave-local write->read

        // ctx_aug += P @ [V | 1]
        #pragma unroll
        for (int ks = 0; ks < 2; ++ks) {
            bf16x8 pf0 = *(const bf16x8*)tile_ptr(Pw[wave], l16, ks * 4 + quad);
            bf16x8 pf1 = *(const bf16x8*)tile_ptr(Pw[wave], 16 + l16, ks * 4 + quad);
            #pragma unroll
            for (int n = 0; n < 4; ++n) {
                bf16x8 vf = *(const bf16x8*)tile_ptr(Vts, n * 16 + l16, ks * 4 + quad);
                vacc[0][n] = MFMA16(pf0, vf, vacc[0][n]);
                vacc[1][n] = MFMA16(pf1, vf, vacc[1][n]);
            }
            vacc[0][4] = MFMA16(pf0, ones, vacc[0][4]);
            vacc[1][4] = MFMA16(pf1, ones, vacc[1][4]);
        }
    }

    const int bi = head >> 4, h = head & 15;
    #pragma unroll
    for (int half = 0; half < 2; ++half) {
        #pragma unroll
        for (int rg = 0; rg < 4; ++rg) {
            const float l = __shfl(vacc[half][4][rg], lane & 48, 64);
            const float inv = 1.0f / l;
            const int si = qt * 128 + wave * 32 + half * 16 + quad * 4 + rg;
            #pragma unroll
            for (int n = 0; n < 4; ++n)
                Ctx[((size_t)si * 8 + bi) * 1024 + h * 64 + n * 16 + l16] =
                    (bf16_t)(vacc[half][n][rg] * inv);
        }
    }
}

// ---------------------------------------------------------------------------
// Kernel 3: output projection (m97 structure).
// ---------------------------------------------------------------------------
__global__ void __launch_bounds__(256) k_out(
    const bf16_t* __restrict__ A, const bf16_t* __restrict__ W,
    const float* __restrict__ bias, float* __restrict__ out)
{
    __shared__ bf16_t As[128 * 64];
    __shared__ bf16_t Bs[128 * 64];
    const int m0 = blockIdx.x * 128;
    const int n0 = blockIdx.y * 128;
    const int t = threadIdx.x;
    const int wave = t >> 6, lane = t & 63;
    const int quad = lane >> 4, l16 = lane & 15;
    const int wm = (wave & 1) * 64, wn = (wave >> 1) * 64;

    f32x4 acc[4][4] = {};

    for (int k0 = 0; k0 < 1024; k0 += 64) {
        __syncthreads();
        #pragma unroll
        for (int p = 0; p < 4; ++p) {
            const int rb = wave * 32 + p * 8;
            stage64(A + (size_t)(m0 + rb) * 1024 + k0, 1024, As + rb * 64, lane);
            stage64(W + (size_t)(n0 + rb) * 1024 + k0, 1024, Bs + rb * 64, lane);
        }
        __syncthreads();
        #pragma unroll
        for (int ks = 0; ks < 2; ++ks) {
            bf16x8 af[4], bf[4];
            #pragma unroll
            for (int i = 0; i < 4; ++i)
                af[i] = *(const bf16x8*)tile_ptr(As, wm + i * 16 + l16, ks * 4 + quad);
            #pragma unroll
            for (int j = 0; j < 4; ++j)
                bf[j] = *(const bf16x8*)tile_ptr(Bs, wn + j * 16 + l16, ks * 4 + quad);
            #pragma unroll
            for (int i = 0; i < 4; ++i)
                #pragma unroll
                for (int j = 0; j < 4; ++j)
                    acc[i][j] = MFMA16(af[i], bf[j], acc[i][j]);
        }
    }

    #pragma unroll
    for (int j = 0; j < 4; ++j) {
        const int n = n0 + wn + j * 16 + l16;
        const float bv = bias[n];
        #pragma unroll
        for (int i = 0; i < 4; ++i) {
            #pragma unroll
            for (int rg = 0; rg < 4; ++rg) {
                const int m = m0 + wm + i * 16 + quad * 4 + rg;
                out[(size_t)m * 1024 + n] = acc[i][j][rg] + bv;
            }
        }
    }
}

// ---------------------------------------------------------------------------
extern "C" void kernel_launch(void* const* d_in, const int* in_sizes, int n_in,
                              void* d_out, int out_size, void* d_ws, size_t ws_size,
                              hipStream_t stream)
{
    const float* query = (const float*)d_in[0];
    const float* in_w  = (const float*)d_in[3];
    const float* in_b  = (const float*)d_in[4];
    const float* out_w = (const float*)d_in[5];
    const float* out_b = (const float*)d_in[6];
    float* out = (float*)d_out;

    bf16_t* Wi  = (bf16_t*)d_ws;                 //  3,145,728
    bf16_t* Wo  = Wi + (size_t)3145728;          //  1,048,576
    bf16_t* Qh  = Wo + (size_t)1048576;          //  8,388,608
    bf16_t* Kh  = Qh + (size_t)8388608;          //  8,388,608
    bf16_t* Vt  = Kh + (size_t)8388608;          //  8,388,608
    bf16_t* Aq  = Vt + (size_t)8388608;          //  8,388,608 (Ctx after k_qkv)
    bf16_t* Ctx = Aq;

    k_cvt<<<dim3(6144), 256, 0, stream>>>(query, in_w, out_w, Aq, Wi, Wo);
    k_qkv<<<dim3(384), 512, 0, stream>>>(Aq, Wi, in_b, Qh, Kh, Vt);
    k_attn<<<dim3(1024), 256, 0, stream>>>(Qh, Kh, Vt, Ctx);
    k_out<<<dim3(64, 8), 256, 0, stream>>>(Ctx, Wo, out_b, out);
}

// Round 3
// 368.675 us; speedup vs baseline: 1.0051x; 1.0051x over previous
//
#include <hip/hip_runtime.h>

typedef __bf16 bf16_t;
typedef __bf16 bf16x4 __attribute__((ext_vector_type(4)));
typedef __bf16 bf16x8 __attribute__((ext_vector_type(8)));
typedef float f32x4 __attribute__((ext_vector_type(4)));

#define MFMA16(a, b, c) __builtin_amdgcn_mfma_f32_16x16x32_bf16((a), (b), (c), 0, 0, 0)

// ---------------------------------------------------------------------------
// Swizzled 64-col bf16 tile helpers (stage + frag-read sides use same swizzle).
// ---------------------------------------------------------------------------
__device__ __forceinline__ const bf16_t* tile_ptr(const bf16_t* t, int row, int kchunk) {
    return t + row * 64 + (((kchunk ^ (row & 7))) << 3);
}

__device__ __forceinline__ void stage64(const bf16_t* __restrict__ gbase, size_t gstride,
                                        bf16_t* lds_rowbase, int lane) {
    const int rr = lane >> 3, cl = lane & 7;
    const bf16_t* g = gbase + (size_t)rr * gstride + ((cl ^ rr) << 3);
    __builtin_amdgcn_global_load_lds((__attribute__((address_space(1))) const void*)g,
                                     (__attribute__((address_space(3))) void*)lds_rowbase,
                                     16, 0, 0);
}

// ---------------------------------------------------------------------------
// Kernel 0: fp32 -> bf16 conversion pre-pass.
// ---------------------------------------------------------------------------
__global__ void __launch_bounds__(256) k_cvt(
    const float* __restrict__ q, const float* __restrict__ wi, const float* __restrict__ wo,
    bf16_t* __restrict__ qb, bf16_t* __restrict__ wib, bf16_t* __restrict__ wob)
{
    const int g = blockIdx.x * 256 + threadIdx.x;
    const float* src; bf16_t* dst; int off;
    if (g < 1048576)      { src = q;  dst = qb;  off = g; }
    else if (g < 1441792) { src = wi; dst = wib; off = g - 1048576; }
    else                  { src = wo; dst = wob; off = g - 1441792; }
    const float4* s4 = (const float4*)(src + (size_t)off * 8);
    float4 a = s4[0], b = s4[1];
    bf16x8 v;
    v[0] = (bf16_t)a.x; v[1] = (bf16_t)a.y; v[2] = (bf16_t)a.z; v[3] = (bf16_t)a.w;
    v[4] = (bf16_t)b.x; v[5] = (bf16_t)b.y; v[6] = (bf16_t)b.z; v[7] = (bf16_t)b.w;
    *(bf16x8*)(dst + (size_t)off * 8) = v;
}

// ---------------------------------------------------------------------------
// Kernel 1: QKV projection — 256x256-tile, 8-wave, 8-phase pipelined schedule
// with COUNTED vmcnt (T4).
//   launch_bounds(512, 1): block uses 128 KiB LDS -> only 1 block/CU can be
//   resident anyway; the earlier (512,2) capped VGPRs at 128 while the wave
//   tile needs ~200 (acc[8][4] alone = 128) -> massive scratch spill
//   (WRITE_SIZE 49->81 MB). (512,1) lifts the cap; 8 waves/CU needs <=256
//   VGPRs, which fits.
//   Qh/Kh: [head][si][d]  (Q scaled by (1/8)*log2(e) -- exp2 fold)
//   Vt:    [head][si>>3][d][si&7]
// ---------------------------------------------------------------------------
__global__ void __launch_bounds__(512, 1) k_qkv(
    const bf16_t* __restrict__ A, const bf16_t* __restrict__ W,
    const float* __restrict__ bias,
    bf16_t* __restrict__ Qh, bf16_t* __restrict__ Kh, bf16_t* __restrict__ Vt)
{
    __shared__ bf16_t smem[65536];          // 128 KiB: [As0|Bs0|As1|Bs1]; Cs in epilogue
    bf16_t* const As0 = smem;
    bf16_t* const Bs0 = smem + 16384;
    bf16_t* const As1 = smem + 32768;
    bf16_t* const Bs1 = smem + 49152;

    // XCD-chunked bijective swizzle (384 blocks, 48/XCD); n fastest inside a
    // chunk so the 12 blocks sharing an A m-panel land on one XCD's L2.
    const int bid = blockIdx.x;
    const int swz = (bid & 7) * 48 + (bid >> 3);
    const int mblk = swz / 12, nblk = swz - mblk * 12;
    const int m0 = mblk * 256;
    const int n0 = nblk * 256;              // permuted n' space
    const int which = n0 >> 10;             // 0=Q, 1=K, 2=V (block-uniform)
    const int hb0 = (n0 & 1023) >> 6;       // first of 4 head-units in this tile
    const int t = threadIdx.x;
    const int wid = t >> 6, lane = t & 63;
    const int quad = lane >> 4, l16 = lane & 15;
    const int wm = (wid >> 2) * 128, wn = (wid & 3) * 64;   // wave tile 128x64

    f32x4 acc[8][4] = {};

    auto stA = [&](bf16_t* dst, int kt, int p) {
        const int rb = wid * 32 + p * 8;
        stage64(A + (size_t)(m0 + rb) * 1024 + kt * 64, 1024, dst + rb * 64, lane);
    };
    auto stB = [&](bf16_t* dst, int kt, int p) {
        const int rb = wid * 32 + p * 8;
        const int np = n0 + rb;
        const int wrow = ((np & 1023) >> 6) * 192 + which * 64 + (np & 63);
        stage64(W + (size_t)wrow * 1024 + kt * 64, 1024, dst + rb * 64, lane);
    };

#define FENCE()    asm volatile("" ::: "memory")
#define BAR()      do { FENCE(); __builtin_amdgcn_s_barrier(); FENCE(); } while (0)
#define WAIT_LDS() asm volatile("s_waitcnt lgkmcnt(0)" ::: "memory")
#define WAIT_VM4() asm volatile("s_waitcnt vmcnt(4)" ::: "memory")
#define WAIT_VM0() asm volatile("s_waitcnt vmcnt(0)" ::: "memory")

#define LOAD_AF(BUF, KS) { _Pragma("unroll") for (int i = 0; i < 8; ++i) \
        af[i] = *(const bf16x8*)tile_ptr((BUF), wm + i * 16 + l16, (KS) * 4 + quad); }
#define LOAD_B(BUF, J0, KS) { \
        b0 = *(const bf16x8*)tile_ptr((BUF), wn + (J0) * 16 + l16, (KS) * 4 + quad); \
        b1 = *(const bf16x8*)tile_ptr((BUF), wn + (J0) * 16 + 16 + l16, (KS) * 4 + quad); }
#define MM16(J0) { __builtin_amdgcn_s_setprio(1); \
        _Pragma("unroll") for (int i = 0; i < 8; ++i) { \
            acc[i][J0] = MFMA16(af[i], b0, acc[i][J0]); \
            acc[i][(J0) + 1] = MFMA16(af[i], b1, acc[i][(J0) + 1]); } \
        __builtin_amdgcn_s_setprio(0); }

    // One K-tile (BK=64) = 4 phases of 16 MFMA, consuming CA/CB.
    // OA/OB = other buffer (tile tt+1 lands there).
    auto ktile = [&](bf16_t* CA, bf16_t* CB, bf16_t* OA, bf16_t* OB, int tt) {
        bf16x8 af[8], b0, b1;
        // ---- phase 1: ds af(ks0)+b01(ks0); issue last-4 of tile tt+1 ----
        LOAD_AF(CA, 0); LOAD_B(CB, 0, 0);
        if (tt < 15) { stA(OA, tt + 1, 2); stB(OB, tt + 1, 2);
                       stA(OA, tt + 1, 3); stB(OB, tt + 1, 3); }
        BAR(); WAIT_LDS(); MM16(0); BAR();
        // ---- phase 2: ds b23(ks0) ----
        LOAD_B(CB, 2, 0);
        BAR(); WAIT_LDS(); MM16(2); BAR();
        // ---- phase 3: ds af(ks1)+b01(ks1) ----
        LOAD_AF(CA, 1); LOAD_B(CB, 0, 1);
        BAR(); WAIT_LDS(); MM16(0); BAR();
        // ---- phase 4: ds b23(ks1) ----
        LOAD_B(CB, 2, 1);
        BAR(); WAIT_LDS(); MM16(2); BAR();
        // ---- boundary: CA/CB now dead (all reads completed before the end
        // barrier). Issue first-4 of tile tt+2 into them, counted wait. ----
        if (tt < 14) {
            stA(CA, tt + 2, 0); stB(CB, tt + 2, 0);
            stA(CA, tt + 2, 1); stB(CB, tt + 2, 1);
            WAIT_VM4();                     // all of tile tt+1 landed; 4 in flight
        } else {
            WAIT_VM0();                     // tail: no younger loads to count
        }
        BAR();
    };

    // Prologue: all 8 of tile 0 -> buf0, first-4 of tile 1 -> buf1.
    #pragma unroll
    for (int p = 0; p < 4; ++p) { stA(As0, 0, p); stB(Bs0, 0, p); }
    stA(As1, 1, 0); stB(Bs1, 1, 0); stA(As1, 1, 1); stB(Bs1, 1, 1);
    WAIT_VM4(); BAR();

    #pragma unroll 1
    for (int it = 0; it < 8; ++it) {
        ktile(As0, Bs0, As1, Bs1, 2 * it);
        ktile(As1, Bs1, As0, Bs0, 2 * it + 1);
    }

    // ---- Epilogue phase 1: C tile (bias+scale applied) -> swizzled LDS ----
    // All staging quiesced by the t=14/15 vmcnt(0) waits; smem reused as Cs[256][256].
    const float scalev = (which == 0) ? 0.180336880111112f : 1.0f;  // 1/8 * log2(e)
    #pragma unroll
    for (int j = 0; j < 4; ++j) {
        const int nl = wn + j * 16 + l16;
        const float bv = bias[(hb0 + (nl >> 6)) * 192 + which * 64 + (nl & 63)];
        #pragma unroll
        for (int i = 0; i < 8; ++i) {
            #pragma unroll
            for (int rg = 0; rg < 4; ++rg) {
                const int ml = wm + i * 16 + quad * 4 + rg;
                smem[ml * 256 + (((nl >> 3) ^ ((ml >> 3) & 7)) << 3) + (nl & 7)] =
                    (bf16_t)((acc[i][j][rg] + bv) * scalev);
            }
        }
    }
    __syncthreads();

    // ---- Epilogue phase 2: coalesced stores (8 waves) ----
    const int si0 = m0 >> 3;
    if (which < 2) {
        bf16_t* dst = which ? Kh : Qh;
        #pragma unroll
        for (int u = 0; u < 4; ++u) {
            const int unit = wid * 4 + u;           // (h, bi), 32 units
            const int h = unit >> 3, bi = unit & 7;
            const int head = bi * 16 + hb0 + h;
            #pragma unroll
            for (int pass = 0; pass < 4; ++pass) {
                const int si = pass * 8 + (lane >> 3);
                const int dc = lane & 7;
                const int ml = si * 8 + bi;
                const int nch = (h * 8 + dc) ^ (si & 7);
                bf16x8 v = *(const bf16x8*)&smem[ml * 256 + nch * 8];
                *(bf16x8*)(dst + (size_t)head * 65536 + (size_t)(si0 + si) * 64 + dc * 8) = v;
            }
        }
    } else {
        #pragma unroll
        for (int u = 0; u < 16; ++u) {
            const int unit = wid * 16 + u;          // (h, bi, c), 128 units
            const int h = unit >> 5, bi = (unit >> 2) & 7, c = unit & 3;
            const int head = bi * 16 + hb0 + h;
            const int d = lane;
            bf16x8 v;
            #pragma unroll
            for (int e = 0; e < 8; ++e) {
                const int ml = (c * 8 + e) * 8 + bi;
                const int nch = (h * 8 + (d >> 3)) ^ e;
                v[e] = smem[ml * 256 + nch * 8 + (d & 7)];
            }
            *(bf16x8*)(Vt + (size_t)head * 65536 +
                       (size_t)(si0 / 8 + c) * 512 + (size_t)d * 8) = v;
        }
    }
#undef FENCE
#undef BAR
#undef WAIT_LDS
#undef WAIT_VM4
#undef WAIT_VM0
#undef LOAD_AF
#undef LOAD_B
#undef MM16
}

// ---------------------------------------------------------------------------
// Kernel 2: fused attention. Block = (head, 128-row q-tile); wave owns 32
// q-rows. S^T computed via MFMA(K,Q) so P-writes are b64 (4 consecutive keys
// per lane). Q frags straight from global; ones-column frag synthesized in
// regs. XCD-affine block swizzle: a head's 8 q-tiles share one XCD's L2.
// ---------------------------------------------------------------------------
__global__ void __launch_bounds__(256, 4) k_attn(
    const bf16_t* __restrict__ Qh, const bf16_t* __restrict__ Kh,
    const bf16_t* __restrict__ Vg, bf16_t* __restrict__ Ctx)
{
    __shared__ bf16_t Ks[64 * 64];
    __shared__ bf16_t Vts[64 * 64];     // V^T tile (rows=d, cols=key), XOR-swizzled
    __shared__ bf16_t Pw[4][32 * 64];   // per-wave P [qrow][key], XOR-swizzled

    const int bid = blockIdx.x;
    const int head = (bid & 7) * 16 + ((bid >> 3) & 15);  // bid%8 = XCD (heuristic)
    const int qt = bid >> 7;
    const int t = threadIdx.x;
    const int wave = t >> 6, lane = t & 63;
    const int quad = lane >> 4, l16 = lane & 15;

    const bf16_t* Qg = Qh + (size_t)head * 65536 + (size_t)qt * 8192;
    const bf16_t* Kg = Kh + (size_t)head * 65536;
    const bf16_t* Vgh = Vg + (size_t)head * 65536;   // [sc][d][s7]

    // Q b-frags from global: lane l16 = q-row, 16B contiguous per lane
    bf16x8 qf[2][2];
    #pragma unroll
    for (int half = 0; half < 2; ++half)
        #pragma unroll
        for (int ks = 0; ks < 2; ++ks)
            qf[half][ks] = *(const bf16x8*)(
                Qg + (size_t)(wave * 32 + half * 16 + l16) * 64 + ks * 32 + quad * 8);

    // ones-column B-frag: column 64 of [V | 1 | 0] augmentation -> l16==0 lanes
    bf16x8 ones;
    #pragma unroll
    for (int e = 0; e < 8; ++e) ones[e] = (bf16_t)((l16 == 0) ? 1.0f : 0.0f);

    f32x4 vacc[2][5] = {};

    for (int kt = 0; kt < 16; ++kt) {
        __syncthreads();
        #pragma unroll
        for (int p = 0; p < 2; ++p) {
            const int rb = wave * 16 + p * 8;
            stage64(Kg + (size_t)(kt * 64 + rb) * 64, 64, Ks + rb * 64, lane);
            {   // V^T staging from [sc][d][s7]
                const int rr = lane >> 3, cl = lane & 7;
                const bf16_t* g = Vgh + (size_t)(kt * 8 + (cl ^ rr)) * 512
                                      + (size_t)(rb + rr) * 8;
                __builtin_amdgcn_global_load_lds(
                    (__attribute__((address_space(1))) const void*)g,
                    (__attribute__((address_space(3))) void*)(Vts + rb * 64), 16, 0, 0);
            }
        }
        __syncthreads();

        // S^T = K Q^T : D[key][qrow]; lane holds keys quad*4+rg (consecutive!)
        f32x4 s[2][4] = {};
        #pragma unroll
        for (int ks = 0; ks < 2; ++ks) {
            #pragma unroll
            for (int j = 0; j < 4; ++j) {
                bf16x8 kf = *(const bf16x8*)tile_ptr(Ks, j * 16 + l16, ks * 4 + quad);
                s[0][j] = MFMA16(kf, qf[0][ks], s[0][j]);
                s[1][j] = MFMA16(kf, qf[1][ks], s[1][j]);
            }
        }

        // P = exp2(S) -> Pw[qrow][key], 4 consecutive keys per lane = b64 write
        #pragma unroll
        for (int half = 0; half < 2; ++half) {
            const int row = half * 16 + l16;
            #pragma unroll
            for (int j = 0; j < 4; ++j) {
                bf16x4 pv;
                #pragma unroll
                for (int rg = 0; rg < 4; ++rg)
                    pv[rg] = (bf16_t)exp2f(s[half][j][rg]);
                const int chunk = j * 2 + (quad >> 1);
                *(bf16x4*)&Pw[wave][row * 64 + ((chunk ^ (row & 7)) << 3) + (quad & 1) * 4] = pv;
            }
        }
        asm volatile("s_waitcnt lgkmcnt(0)" ::: "memory");  // wave-local write->read

        // ctx_aug += P @ [V | 1]
        #pragma unroll
        for (int ks = 0; ks < 2; ++ks) {
            bf16x8 pf0 = *(const bf16x8*)tile_ptr(Pw[wave], l16, ks * 4 + quad);
            bf16x8 pf1 = *(const bf16x8*)tile_ptr(Pw[wave], 16 + l16, ks * 4 + quad);
            #pragma unroll
            for (int n = 0; n < 4; ++n) {
                bf16x8 vf = *(const bf16x8*)tile_ptr(Vts, n * 16 + l16, ks * 4 + quad);
                vacc[0][n] = MFMA16(pf0, vf, vacc[0][n]);
                vacc[1][n] = MFMA16(pf1, vf, vacc[1][n]);
            }
            vacc[0][4] = MFMA16(pf0, ones, vacc[0][4]);
            vacc[1][4] = MFMA16(pf1, ones, vacc[1][4]);
        }
    }

    const int bi = head >> 4, h = head & 15;
    #pragma unroll
    for (int half = 0; half < 2; ++half) {
        #pragma unroll
        for (int rg = 0; rg < 4; ++rg) {
            const float l = __shfl(vacc[half][4][rg], lane & 48, 64);
            const float inv = 1.0f / l;
            const int si = qt * 128 + wave * 32 + half * 16 + quad * 4 + rg;
            #pragma unroll
            for (int n = 0; n < 4; ++n)
                Ctx[((size_t)si * 8 + bi) * 1024 + h * 64 + n * 16 + l16] =
                    (bf16_t)(vacc[half][n][rg] * inv);
        }
    }
}

// ---------------------------------------------------------------------------
// Kernel 3: output projection (m97 structure).
// ---------------------------------------------------------------------------
__global__ void __launch_bounds__(256) k_out(
    const bf16_t* __restrict__ A, const bf16_t* __restrict__ W,
    const float* __restrict__ bias, float* __restrict__ out)
{
    __shared__ bf16_t As[128 * 64];
    __shared__ bf16_t Bs[128 * 64];
    const int m0 = blockIdx.x * 128;
    const int n0 = blockIdx.y * 128;
    const int t = threadIdx.x;
    const int wave = t >> 6, lane = t & 63;
    const int quad = lane >> 4, l16 = lane & 15;
    const int wm = (wave & 1) * 64, wn = (wave >> 1) * 64;

    f32x4 acc[4][4] = {};

    for (int k0 = 0; k0 < 1024; k0 += 64) {
        __syncthreads();
        #pragma unroll
        for (int p = 0; p < 4; ++p) {
            const int rb = wave * 32 + p * 8;
            stage64(A + (size_t)(m0 + rb) * 1024 + k0, 1024, As + rb * 64, lane);
            stage64(W + (size_t)(n0 + rb) * 1024 + k0, 1024, Bs + rb * 64, lane);
        }
        __syncthreads();
        #pragma unroll
        for (int ks = 0; ks < 2; ++ks) {
            bf16x8 af[4], bf[4];
            #pragma unroll
            for (int i = 0; i < 4; ++i)
                af[i] = *(const bf16x8*)tile_ptr(As, wm + i * 16 + l16, ks * 4 + quad);
            #pragma unroll
            for (int j = 0; j < 4; ++j)
                bf[j] = *(const bf16x8*)tile_ptr(Bs, wn + j * 16 + l16, ks * 4 + quad);
            #pragma unroll
            for (int i = 0; i < 4; ++i)
                #pragma unroll
                for (int j = 0; j < 4; ++j)
                    acc[i][j] = MFMA16(af[i], bf[j], acc[i][j]);
        }
    }

    #pragma unroll
    for (int j = 0; j < 4; ++j) {
        const int n = n0 + wn + j * 16 + l16;
        const float bv = bias[n];
        #pragma unroll
        for (int i = 0; i < 4; ++i) {
            #pragma unroll
            for (int rg = 0; rg < 4; ++rg) {
                const int m = m0 + wm + i * 16 + quad * 4 + rg;
                out[(size_t)m * 1024 + n] = acc[i][j][rg] + bv;
            }
        }
    }
}

// ---------------------------------------------------------------------------
extern "C" void kernel_launch(void* const* d_in, const int* in_sizes, int n_in,
                              void* d_out, int out_size, void* d_ws, size_t ws_size,
                              hipStream_t stream)
{
    const float* query = (const float*)d_in[0];
    const float* in_w  = (const float*)d_in[3];
    const float* in_b  = (const float*)d_in[4];
    const float* out_w = (const float*)d_in[5];
    const float* out_b = (const float*)d_in[6];
    float* out = (float*)d_out;

    bf16_t* Wi  = (bf16_t*)d_ws;                 //  3,145,728
    bf16_t* Wo  = Wi + (size_t)3145728;          //  1,048,576
    bf16_t* Qh  = Wo + (size_t)1048576;          //  8,388,608
    bf16_t* Kh  = Qh + (size_t)8388608;          //  8,388,608
    bf16_t* Vt  = Kh + (size_t)8388608;          //  8,388,608
    bf16_t* Aq  = Vt + (size_t)8388608;          //  8,388,608 (Ctx after k_qkv)
    bf16_t* Ctx = Aq;

    k_cvt<<<dim3(6144), 256, 0, stream>>>(query, in_w, out_w, Aq, Wi, Wo);
    k_qkv<<<dim3(384), 512, 0, stream>>>(Aq, Wi, in_b, Qh, Kh, Vt);
    k_attn<<<dim3(1024), 256, 0, stream>>>(Qh, Kh, Vt, Ctx);
    k_out<<<dim3(64, 8), 256, 0, stream>>>(Ctx, Wo, out_b, out);
}

// Round 4
// 328.228 us; speedup vs baseline: 1.1290x; 1.1232x over previous
//
#include <hip/hip_runtime.h>

typedef __bf16 bf16_t;
typedef __bf16 bf16x4 __attribute__((ext_vector_type(4)));
typedef __bf16 bf16x8 __attribute__((ext_vector_type(8)));
typedef float f32x4 __attribute__((ext_vector_type(4)));

#define MFMA16(a, b, c) __builtin_amdgcn_mfma_f32_16x16x32_bf16((a), (b), (c), 0, 0, 0)

// ---------------------------------------------------------------------------
// Swizzled 64-col bf16 tile helpers (stage + frag-read sides use same swizzle).
// ---------------------------------------------------------------------------
__device__ __forceinline__ const bf16_t* tile_ptr(const bf16_t* t, int row, int kchunk) {
    return t + row * 64 + (((kchunk ^ (row & 7))) << 3);
}

__device__ __forceinline__ void stage64(const bf16_t* __restrict__ gbase, size_t gstride,
                                        bf16_t* lds_rowbase, int lane) {
    const int rr = lane >> 3, cl = lane & 7;
    const bf16_t* g = gbase + (size_t)rr * gstride + ((cl ^ rr) << 3);
    __builtin_amdgcn_global_load_lds((__attribute__((address_space(1))) const void*)g,
                                     (__attribute__((address_space(3))) void*)lds_rowbase,
                                     16, 0, 0);
}

// ---------------------------------------------------------------------------
// Kernel 0: fp32 -> bf16 conversion pre-pass.
// ---------------------------------------------------------------------------
__global__ void __launch_bounds__(256) k_cvt(
    const float* __restrict__ q, const float* __restrict__ wi, const float* __restrict__ wo,
    bf16_t* __restrict__ qb, bf16_t* __restrict__ wib, bf16_t* __restrict__ wob)
{
    const int g = blockIdx.x * 256 + threadIdx.x;
    const float* src; bf16_t* dst; int off;
    if (g < 1048576)      { src = q;  dst = qb;  off = g; }
    else if (g < 1441792) { src = wi; dst = wib; off = g - 1048576; }
    else                  { src = wo; dst = wob; off = g - 1441792; }
    const float4* s4 = (const float4*)(src + (size_t)off * 8);
    float4 a = s4[0], b = s4[1];
    bf16x8 v;
    v[0] = (bf16_t)a.x; v[1] = (bf16_t)a.y; v[2] = (bf16_t)a.z; v[3] = (bf16_t)a.w;
    v[4] = (bf16_t)b.x; v[5] = (bf16_t)b.y; v[6] = (bf16_t)b.z; v[7] = (bf16_t)b.w;
    *(bf16x8*)(dst + (size_t)off * 8) = v;
}

// ---------------------------------------------------------------------------
// Kernel 1: QKV projection — 256x256-tile, 8-wave, 8-phase pipelined schedule
// with COUNTED vmcnt (T4). HOT PATH IS FULLY MACRO-FLATTENED: rounds 2/3
// wrapped it in a by-reference-capturing lambda; when clang declined to
// inline it, acc[8][4] was forced into scratch (VGPR_Count=128, +32MB
// scratch writes/dispatch, 2x slowdown). No calls remain in the loop.
//   Qh/Kh: [head][si][d]  (Q scaled by (1/8)*log2(e) -- exp2 fold)
//   Vt:    [head][si>>3][d][si&7]
// ---------------------------------------------------------------------------
__global__ void __launch_bounds__(512, 1) k_qkv(
    const bf16_t* __restrict__ A, const bf16_t* __restrict__ W,
    const float* __restrict__ bias,
    bf16_t* __restrict__ Qh, bf16_t* __restrict__ Kh, bf16_t* __restrict__ Vt)
{
    __shared__ bf16_t smem[65536];          // 128 KiB: [As0|Bs0|As1|Bs1]; Cs in epilogue
    bf16_t* const As0 = smem;
    bf16_t* const Bs0 = smem + 16384;
    bf16_t* const As1 = smem + 32768;
    bf16_t* const Bs1 = smem + 49152;

    // XCD-chunked bijective swizzle (384 blocks, 48/XCD); n fastest inside a
    // chunk so the 12 blocks sharing an A m-panel land on one XCD's L2.
    const int bid = blockIdx.x;
    const int swz = (bid & 7) * 48 + (bid >> 3);
    const int mblk = swz / 12, nblk = swz - mblk * 12;
    const int m0 = mblk * 256;
    const int n0 = nblk * 256;              // permuted n' space
    const int which = n0 >> 10;             // 0=Q, 1=K, 2=V (block-uniform)
    const int hb0 = (n0 & 1023) >> 6;       // first of 4 head-units in this tile
    const int t = threadIdx.x;
    const int wid = t >> 6, lane = t & 63;
    const int quad = lane >> 4, l16 = lane & 15;
    const int wm = (wid >> 2) * 128, wn = (wid & 3) * 64;   // wave tile 128x64

    f32x4 acc[8][4] = {};

#define STA(DST, KT, P) { const int rb_ = wid * 32 + (P) * 8;                 \
        stage64(A + (size_t)(m0 + rb_) * 1024 + (KT) * 64, 1024,              \
                (DST) + rb_ * 64, lane); }
#define STB(DST, KT, P) { const int rb_ = wid * 32 + (P) * 8;                 \
        const int np_ = n0 + rb_;                                             \
        const int wrow_ = ((np_ & 1023) >> 6) * 192 + which * 64 + (np_ & 63);\
        stage64(W + (size_t)wrow_ * 1024 + (KT) * 64, 1024,                   \
                (DST) + rb_ * 64, lane); }

#define FENCE()    asm volatile("" ::: "memory")
#define BAR()      do { FENCE(); __builtin_amdgcn_s_barrier(); FENCE(); } while (0)
#define WAIT_LDS() asm volatile("s_waitcnt lgkmcnt(0)" ::: "memory")
#define WAIT_VM4() asm volatile("s_waitcnt vmcnt(4)" ::: "memory")
#define WAIT_VM0() asm volatile("s_waitcnt vmcnt(0)" ::: "memory")

#define LOAD_AF(BUF, KS) { _Pragma("unroll") for (int i = 0; i < 8; ++i)      \
        af[i] = *(const bf16x8*)tile_ptr((BUF), wm + i * 16 + l16, (KS) * 4 + quad); }
#define LOAD_B(BUF, J0, KS) {                                                 \
        b0 = *(const bf16x8*)tile_ptr((BUF), wn + (J0) * 16 + l16, (KS) * 4 + quad); \
        b1 = *(const bf16x8*)tile_ptr((BUF), wn + (J0) * 16 + 16 + l16, (KS) * 4 + quad); }
#define MM16(J0) { __builtin_amdgcn_s_setprio(1);                             \
        _Pragma("unroll") for (int i = 0; i < 8; ++i) {                       \
            acc[i][J0] = MFMA16(af[i], b0, acc[i][J0]);                       \
            acc[i][(J0) + 1] = MFMA16(af[i], b1, acc[i][(J0) + 1]); }         \
        __builtin_amdgcn_s_setprio(0); }

    // One K-tile (BK=64) = 4 phases of 16 MFMA, consuming CA/CB.
    // OA/OB = other buffer (tile TT+1 lands there). Boundary: CA/CB dead
    // after the end barrier -> issue first-4 of tile TT+2 into them, then
    // counted vmcnt(4) = all of tile TT+1 landed, TT+2's 4 still in flight.
#define KTILE(CA, CB, OA, OB, TT) {                                           \
        bf16x8 af[8], b0, b1;                                                 \
        LOAD_AF(CA, 0); LOAD_B(CB, 0, 0);                                     \
        if ((TT) < 15) { STA(OA, (TT) + 1, 2); STB(OB, (TT) + 1, 2);          \
                         STA(OA, (TT) + 1, 3); STB(OB, (TT) + 1, 3); }        \
        BAR(); WAIT_LDS(); MM16(0); BAR();                                    \
        LOAD_B(CB, 2, 0);                                                     \
        BAR(); WAIT_LDS(); MM16(2); BAR();                                    \
        LOAD_AF(CA, 1); LOAD_B(CB, 0, 1);                                     \
        BAR(); WAIT_LDS(); MM16(0); BAR();                                    \
        LOAD_B(CB, 2, 1);                                                     \
        BAR(); WAIT_LDS(); MM16(2); BAR();                                    \
        if ((TT) < 14) {                                                      \
            STA(CA, (TT) + 2, 0); STB(CB, (TT) + 2, 0);                       \
            STA(CA, (TT) + 2, 1); STB(CB, (TT) + 2, 1);                       \
            WAIT_VM4();                                                       \
        } else { WAIT_VM0(); }                                                \
        BAR(); }

    // Prologue: all 8 of tile 0 -> buf0, first-4 of tile 1 -> buf1.
    #pragma unroll
    for (int p = 0; p < 4; ++p) { STA(As0, 0, p); STB(Bs0, 0, p); }
    STA(As1, 1, 0); STB(Bs1, 1, 0); STA(As1, 1, 1); STB(Bs1, 1, 1);
    WAIT_VM4(); BAR();

    #pragma unroll 1
    for (int it = 0; it < 8; ++it) {
        const int t0 = 2 * it, t1 = 2 * it + 1;
        KTILE(As0, Bs0, As1, Bs1, t0);
        KTILE(As1, Bs1, As0, Bs0, t1);
    }

    // ---- Epilogue phase 1: C tile (bias+scale applied) -> swizzled LDS ----
    // All staging quiesced by the t=14/15 vmcnt(0) waits; smem reused as Cs[256][256].
    const float scalev = (which == 0) ? 0.180336880111112f : 1.0f;  // 1/8 * log2(e)
    #pragma unroll
    for (int j = 0; j < 4; ++j) {
        const int nl = wn + j * 16 + l16;
        const float bv = bias[(hb0 + (nl >> 6)) * 192 + which * 64 + (nl & 63)];
        #pragma unroll
        for (int i = 0; i < 8; ++i) {
            #pragma unroll
            for (int rg = 0; rg < 4; ++rg) {
                const int ml = wm + i * 16 + quad * 4 + rg;
                smem[ml * 256 + (((nl >> 3) ^ ((ml >> 3) & 7)) << 3) + (nl & 7)] =
                    (bf16_t)((acc[i][j][rg] + bv) * scalev);
            }
        }
    }
    __syncthreads();

    // ---- Epilogue phase 2: coalesced stores (8 waves) ----
    const int si0 = m0 >> 3;
    if (which < 2) {
        bf16_t* dst = which ? Kh : Qh;
        #pragma unroll
        for (int u = 0; u < 4; ++u) {
            const int unit = wid * 4 + u;           // (h, bi), 32 units
            const int h = unit >> 3, bi = unit & 7;
            const int head = bi * 16 + hb0 + h;
            #pragma unroll
            for (int pass = 0; pass < 4; ++pass) {
                const int si = pass * 8 + (lane >> 3);
                const int dc = lane & 7;
                const int ml = si * 8 + bi;
                const int nch = (h * 8 + dc) ^ (si & 7);
                bf16x8 v = *(const bf16x8*)&smem[ml * 256 + nch * 8];
                *(bf16x8*)(dst + (size_t)head * 65536 + (size_t)(si0 + si) * 64 + dc * 8) = v;
            }
        }
    } else {
        #pragma unroll
        for (int u = 0; u < 16; ++u) {
            const int unit = wid * 16 + u;          // (h, bi, c), 128 units
            const int h = unit >> 5, bi = (unit >> 2) & 7, c = unit & 3;
            const int head = bi * 16 + hb0 + h;
            const int d = lane;
            bf16x8 v;
            #pragma unroll
            for (int e = 0; e < 8; ++e) {
                const int ml = (c * 8 + e) * 8 + bi;
                const int nch = (h * 8 + (d >> 3)) ^ e;
                v[e] = smem[ml * 256 + nch * 8 + (d & 7)];
            }
            *(bf16x8*)(Vt + (size_t)head * 65536 +
                       (size_t)(si0 / 8 + c) * 512 + (size_t)d * 8) = v;
        }
    }
#undef STA
#undef STB
#undef FENCE
#undef BAR
#undef WAIT_LDS
#undef WAIT_VM4
#undef WAIT_VM0
#undef LOAD_AF
#undef LOAD_B
#undef MM16
#undef KTILE
}

// ---------------------------------------------------------------------------
// Kernel 2: fused attention. Block = (head, 128-row q-tile); wave owns 32
// q-rows. S^T computed via MFMA(K,Q) so P-writes are b64 (4 consecutive keys
// per lane). Q frags straight from global; ones-column frag synthesized in
// regs. XCD-affine block swizzle: a head's 8 q-tiles share one XCD's L2.
// ---------------------------------------------------------------------------
__global__ void __launch_bounds__(256, 4) k_attn(
    const bf16_t* __restrict__ Qh, const bf16_t* __restrict__ Kh,
    const bf16_t* __restrict__ Vg, bf16_t* __restrict__ Ctx)
{
    __shared__ bf16_t Ks[64 * 64];
    __shared__ bf16_t Vts[64 * 64];     // V^T tile (rows=d, cols=key), XOR-swizzled
    __shared__ bf16_t Pw[4][32 * 64];   // per-wave P [qrow][key], XOR-swizzled

    const int bid = blockIdx.x;
    const int head = (bid & 7) * 16 + ((bid >> 3) & 15);  // bid%8 = XCD (heuristic)
    const int qt = bid >> 7;
    const int t = threadIdx.x;
    const int wave = t >> 6, lane = t & 63;
    const int quad = lane >> 4, l16 = lane & 15;

    const bf16_t* Qg = Qh + (size_t)head * 65536 + (size_t)qt * 8192;
    const bf16_t* Kg = Kh + (size_t)head * 65536;
    const bf16_t* Vgh = Vg + (size_t)head * 65536;   // [sc][d][s7]

    // Q b-frags from global: lane l16 = q-row, 16B contiguous per lane
    bf16x8 qf[2][2];
    #pragma unroll
    for (int half = 0; half < 2; ++half)
        #pragma unroll
        for (int ks = 0; ks < 2; ++ks)
            qf[half][ks] = *(const bf16x8*)(
                Qg + (size_t)(wave * 32 + half * 16 + l16) * 64 + ks * 32 + quad * 8);

    // ones-column B-frag: column 64 of [V | 1 | 0] augmentation -> l16==0 lanes
    bf16x8 ones;
    #pragma unroll
    for (int e = 0; e < 8; ++e) ones[e] = (bf16_t)((l16 == 0) ? 1.0f : 0.0f);

    f32x4 vacc[2][5] = {};

    for (int kt = 0; kt < 16; ++kt) {
        __syncthreads();
        #pragma unroll
        for (int p = 0; p < 2; ++p) {
            const int rb = wave * 16 + p * 8;
            stage64(Kg + (size_t)(kt * 64 + rb) * 64, 64, Ks + rb * 64, lane);
            {   // V^T staging from [sc][d][s7]
                const int rr = lane >> 3, cl = lane & 7;
                const bf16_t* g = Vgh + (size_t)(kt * 8 + (cl ^ rr)) * 512
                                      + (size_t)(rb + rr) * 8;
                __builtin_amdgcn_global_load_lds(
                    (__attribute__((address_space(1))) const void*)g,
                    (__attribute__((address_space(3))) void*)(Vts + rb * 64), 16, 0, 0);
            }
        }
        __syncthreads();

        // S^T = K Q^T : D[key][qrow]; lane holds keys quad*4+rg (consecutive!)
        f32x4 s[2][4] = {};
        #pragma unroll
        for (int ks = 0; ks < 2; ++ks) {
            #pragma unroll
            for (int j = 0; j < 4; ++j) {
                bf16x8 kf = *(const bf16x8*)tile_ptr(Ks, j * 16 + l16, ks * 4 + quad);
                s[0][j] = MFMA16(kf, qf[0][ks], s[0][j]);
                s[1][j] = MFMA16(kf, qf[1][ks], s[1][j]);
            }
        }

        // P = exp2(S) -> Pw[qrow][key], 4 consecutive keys per lane = b64 write
        #pragma unroll
        for (int half = 0; half < 2; ++half) {
            const int row = half * 16 + l16;
            #pragma unroll
            for (int j = 0; j < 4; ++j) {
                bf16x4 pv;
                #pragma unroll
                for (int rg = 0; rg < 4; ++rg)
                    pv[rg] = (bf16_t)exp2f(s[half][j][rg]);
                const int chunk = j * 2 + (quad >> 1);
                *(bf16x4*)&Pw[wave][row * 64 + ((chunk ^ (row & 7)) << 3) + (quad & 1) * 4] = pv;
            }
        }
        asm volatile("s_waitcnt lgkmcnt(0)" ::: "memory");  // wave-local write->read

        // ctx_aug += P @ [V | 1]
        #pragma unroll
        for (int ks = 0; ks < 2; ++ks) {
            bf16x8 pf0 = *(const bf16x8*)tile_ptr(Pw[wave], l16, ks * 4 + quad);
            bf16x8 pf1 = *(const bf16x8*)tile_ptr(Pw[wave], 16 + l16, ks * 4 + quad);
            #pragma unroll
            for (int n = 0; n < 4; ++n) {
                bf16x8 vf = *(const bf16x8*)tile_ptr(Vts, n * 16 + l16, ks * 4 + quad);
                vacc[0][n] = MFMA16(pf0, vf, vacc[0][n]);
                vacc[1][n] = MFMA16(pf1, vf, vacc[1][n]);
            }
            vacc[0][4] = MFMA16(pf0, ones, vacc[0][4]);
            vacc[1][4] = MFMA16(pf1, ones, vacc[1][4]);
        }
    }

    const int bi = head >> 4, h = head & 15;
    #pragma unroll
    for (int half = 0; half < 2; ++half) {
        #pragma unroll
        for (int rg = 0; rg < 4; ++rg) {
            const float l = __shfl(vacc[half][4][rg], lane & 48, 64);
            const float inv = 1.0f / l;
            const int si = qt * 128 + wave * 32 + half * 16 + quad * 4 + rg;
            #pragma unroll
            for (int n = 0; n < 4; ++n)
                Ctx[((size_t)si * 8 + bi) * 1024 + h * 64 + n * 16 + l16] =
                    (bf16_t)(vacc[half][n][rg] * inv);
        }
    }
}

// ---------------------------------------------------------------------------
// Kernel 3: output projection (m97 structure).
// ---------------------------------------------------------------------------
__global__ void __launch_bounds__(256) k_out(
    const bf16_t* __restrict__ A, const bf16_t* __restrict__ W,
    const float* __restrict__ bias, float* __restrict__ out)
{
    __shared__ bf16_t As[128 * 64];
    __shared__ bf16_t Bs[128 * 64];
    const int m0 = blockIdx.x * 128;
    const int n0 = blockIdx.y * 128;
    const int t = threadIdx.x;
    const int wave = t >> 6, lane = t & 63;
    const int quad = lane >> 4, l16 = lane & 15;
    const int wm = (wave & 1) * 64, wn = (wave >> 1) * 64;

    f32x4 acc[4][4] = {};

    for (int k0 = 0; k0 < 1024; k0 += 64) {
        __syncthreads();
        #pragma unroll
        for (int p = 0; p < 4; ++p) {
            const int rb = wave * 32 + p * 8;
            stage64(A + (size_t)(m0 + rb) * 1024 + k0, 1024, As + rb * 64, lane);
            stage64(W + (size_t)(n0 + rb) * 1024 + k0, 1024, Bs + rb * 64, lane);
        }
        __syncthreads();
        #pragma unroll
        for (int ks = 0; ks < 2; ++ks) {
            bf16x8 af[4], bf[4];
            #pragma unroll
            for (int i = 0; i < 4; ++i)
                af[i] = *(const bf16x8*)tile_ptr(As, wm + i * 16 + l16, ks * 4 + quad);
            #pragma unroll
            for (int j = 0; j < 4; ++j)
                bf[j] = *(const bf16x8*)tile_ptr(Bs, wn + j * 16 + l16, ks * 4 + quad);
            #pragma unroll
            for (int i = 0; i < 4; ++i)
                #pragma unroll
                for (int j = 0; j < 4; ++j)
                    acc[i][j] = MFMA16(af[i], bf[j], acc[i][j]);
        }
    }

    #pragma unroll
    for (int j = 0; j < 4; ++j) {
        const int n = n0 + wn + j * 16 + l16;
        const float bv = bias[n];
        #pragma unroll
        for (int i = 0; i < 4; ++i) {
            #pragma unroll
            for (int rg = 0; rg < 4; ++rg) {
                const int m = m0 + wm + i * 16 + quad * 4 + rg;
                out[(size_t)m * 1024 + n] = acc[i][j][rg] + bv;
            }
        }
    }
}

// ---------------------------------------------------------------------------
extern "C" void kernel_launch(void* const* d_in, const int* in_sizes, int n_in,
                              void* d_out, int out_size, void* d_ws, size_t ws_size,
                              hipStream_t stream)
{
    const float* query = (const float*)d_in[0];
    const float* in_w  = (const float*)d_in[3];
    const float* in_b  = (const float*)d_in[4];
    const float* out_w = (const float*)d_in[5];
    const float* out_b = (const float*)d_in[6];
    float* out = (float*)d_out;

    bf16_t* Wi  = (bf16_t*)d_ws;                 //  3,145,728
    bf16_t* Wo  = Wi + (size_t)3145728;          //  1,048,576
    bf16_t* Qh  = Wo + (size_t)1048576;          //  8,388,608
    bf16_t* Kh  = Qh + (size_t)8388608;          //  8,388,608
    bf16_t* Vt  = Kh + (size_t)8388608;          //  8,388,608
    bf16_t* Aq  = Vt + (size_t)8388608;          //  8,388,608 (Ctx after k_qkv)
    bf16_t* Ctx = Aq;

    k_cvt<<<dim3(6144), 256, 0, stream>>>(query, in_w, out_w, Aq, Wi, Wo);
    k_qkv<<<dim3(384), 512, 0, stream>>>(Aq, Wi, in_b, Qh, Kh, Vt);
    k_attn<<<dim3(1024), 256, 0, stream>>>(Qh, Kh, Vt, Ctx);
    k_out<<<dim3(64, 8), 256, 0, stream>>>(Ctx, Wo, out_b, out);
}

// Round 5
// 278.555 us; speedup vs baseline: 1.3303x; 1.1783x over previous
//
#include <hip/hip_runtime.h>

typedef __bf16 bf16_t;
typedef __bf16 bf16x4 __attribute__((ext_vector_type(4)));
typedef __bf16 bf16x8 __attribute__((ext_vector_type(8)));
typedef float f32x4 __attribute__((ext_vector_type(4)));

#define MFMA16(a, b, c) __builtin_amdgcn_mfma_f32_16x16x32_bf16((a), (b), (c), 0, 0, 0)

// ---------------------------------------------------------------------------
// Swizzled 64-col bf16 tile helpers (stage + frag-read sides use same swizzle).
// ---------------------------------------------------------------------------
__device__ __forceinline__ const bf16_t* tile_ptr(const bf16_t* t, int row, int kchunk) {
    return t + row * 64 + (((kchunk ^ (row & 7))) << 3);
}

__device__ __forceinline__ void stage64(const bf16_t* __restrict__ gbase, size_t gstride,
                                        bf16_t* lds_rowbase, int lane) {
    const int rr = lane >> 3, cl = lane & 7;
    const bf16_t* g = gbase + (size_t)rr * gstride + ((cl ^ rr) << 3);
    __builtin_amdgcn_global_load_lds((__attribute__((address_space(1))) const void*)g,
                                     (__attribute__((address_space(3))) void*)lds_rowbase,
                                     16, 0, 0);
}

// Swizzled 128x128 bf16 C-tile address (epilogue transpose buffer).
__device__ __forceinline__ int cs_addr(int m, int n) {
    return m * 128 + ((((n >> 3) ^ ((m >> 3) & 7))) << 3) + (n & 7);
}

// ---------------------------------------------------------------------------
// Kernel 0: fp32 -> bf16 conversion pre-pass.
// ---------------------------------------------------------------------------
__global__ void __launch_bounds__(256) k_cvt(
    const float* __restrict__ q, const float* __restrict__ wi, const float* __restrict__ wo,
    bf16_t* __restrict__ qb, bf16_t* __restrict__ wib, bf16_t* __restrict__ wob)
{
    const int g = blockIdx.x * 256 + threadIdx.x;
    const float* src; bf16_t* dst; int off;
    if (g < 1048576)      { src = q;  dst = qb;  off = g; }
    else if (g < 1441792) { src = wi; dst = wib; off = g - 1048576; }
    else                  { src = wo; dst = wob; off = g - 1441792; }
    const float4* s4 = (const float4*)(src + (size_t)off * 8);
    float4 a = s4[0], b = s4[1];
    bf16x8 v;
    v[0] = (bf16_t)a.x; v[1] = (bf16_t)a.y; v[2] = (bf16_t)a.z; v[3] = (bf16_t)a.w;
    v[4] = (bf16_t)b.x; v[5] = (bf16_t)b.y; v[6] = (bf16_t)b.z; v[7] = (bf16_t)b.w;
    *(bf16x8*)(dst + (size_t)off * 8) = v;
}

// ---------------------------------------------------------------------------
// Kernel 1: QKV projection (round-0 proven version: 128x128 tile, 4 waves,
// 80.6 us / 640 TF, zero scratch). The 256x256 8-phase rewrite (rounds 1-4)
// spilled acc to scratch under all variants tried (launch_bounds, lambda ->
// macro flattening): VGPR_Count pinned at 128, +21..32 MB scratch
// writes/dispatch, 1.5-2x slower. Reverted; do not re-attempt without
// disasm evidence that acc stays in registers.
//   Qh/Kh: [head][si][d]  (Q scaled by (1/8)*log2(e) -- exp2 fold)
//   Vt:    [head][si>>3][d][si&7]
// ---------------------------------------------------------------------------
__global__ void __launch_bounds__(256) k_qkv(
    const bf16_t* __restrict__ A, const bf16_t* __restrict__ W,
    const float* __restrict__ bias,
    bf16_t* __restrict__ Qh, bf16_t* __restrict__ Kh, bf16_t* __restrict__ Vt)
{
    __shared__ bf16_t smem[16384];          // As|Bs during K-loop; Cs in epilogue
    bf16_t* As = smem;
    bf16_t* Bs = smem + 8192;
    const int m0 = blockIdx.x * 128;
    const int n0 = blockIdx.y * 128;        // permuted n' space
    const int which = n0 >> 10;             // 0=Q, 1=K, 2=V (block-uniform)
    const int hbase = (n0 & 1023) >> 6;
    const int t = threadIdx.x;
    const int wave = t >> 6, lane = t & 63;
    const int quad = lane >> 4, l16 = lane & 15;
    const int wm = (wave & 1) * 64, wn = (wave >> 1) * 64;

    f32x4 acc[4][4] = {};

    for (int k0 = 0; k0 < 1024; k0 += 64) {
        __syncthreads();
        #pragma unroll
        for (int p = 0; p < 4; ++p) {
            const int rb = wave * 32 + p * 8;
            stage64(A + (size_t)(m0 + rb) * 1024 + k0, 1024, As + rb * 64, lane);
            const int np = n0 + rb;
            const int wrow = ((np & 1023) >> 6) * 192 + which * 64 + (np & 63);
            stage64(W + (size_t)wrow * 1024 + k0, 1024, Bs + rb * 64, lane);
        }
        __syncthreads();
        #pragma unroll
        for (int ks = 0; ks < 2; ++ks) {
            bf16x8 af[4], bf[4];
            #pragma unroll
            for (int i = 0; i < 4; ++i)
                af[i] = *(const bf16x8*)tile_ptr(As, wm + i * 16 + l16, ks * 4 + quad);
            #pragma unroll
            for (int j = 0; j < 4; ++j)
                bf[j] = *(const bf16x8*)tile_ptr(Bs, wn + j * 16 + l16, ks * 4 + quad);
            #pragma unroll
            for (int i = 0; i < 4; ++i)
                #pragma unroll
                for (int j = 0; j < 4; ++j)
                    acc[i][j] = MFMA16(af[i], bf[j], acc[i][j]);
        }
    }

    // ---- Epilogue phase 1: C tile (bias+scale applied) -> swizzled LDS ----
    __syncthreads();
    const float scale = (which == 0) ? 0.180336880111112f : 1.0f;  // 1/8 * log2(e)
    #pragma unroll
    for (int j = 0; j < 4; ++j) {
        const int nl = wn + j * 16 + l16;
        const float bv = bias[(hbase + (nl >> 6)) * 192 + which * 64 + (nl & 63)];
        #pragma unroll
        for (int i = 0; i < 4; ++i) {
            #pragma unroll
            for (int rg = 0; rg < 4; ++rg) {
                const int ml = wm + i * 16 + quad * 4 + rg;
                smem[cs_addr(ml, nl)] = (bf16_t)((acc[i][j][rg] + bv) * scale);
            }
        }
    }
    __syncthreads();

    // ---- Epilogue phase 2: coalesced stores ----
    const int si0 = m0 >> 3;
    if (which < 2) {
        bf16_t* dst = which ? Kh : Qh;
        #pragma unroll
        for (int u = 0; u < 4; ++u) {
            const int unit = wave * 4 + u;          // (h, bi)
            const int h = unit >> 3, bi = unit & 7;
            const int head = bi * 16 + hbase + h;
            #pragma unroll
            for (int pass = 0; pass < 2; ++pass) {
                const int si = pass * 8 + (lane >> 3);
                const int dc = lane & 7;
                const int ml = si * 8 + bi;
                const int nch = (h * 8 + dc) ^ (si & 7);
                bf16x8 v = *(const bf16x8*)&smem[ml * 128 + nch * 8];
                *(bf16x8*)(dst + (size_t)head * 65536 + (size_t)(si0 + si) * 64 + dc * 8) = v;
            }
        }
    } else {
        #pragma unroll
        for (int u = 0; u < 8; ++u) {
            const int unit = wave * 8 + u;          // (h, bi, c)
            const int h = unit >> 4, bi = (unit >> 1) & 7, c = unit & 1;
            const int head = bi * 16 + hbase + h;
            const int d = lane;
            bf16x8 v;
            #pragma unroll
            for (int e = 0; e < 8; ++e) {
                const int ml = (c * 8 + e) * 8 + bi;
                const int nch = (h * 8 + (d >> 3)) ^ e;
                v[e] = smem[ml * 128 + nch * 8 + (d & 7)];
            }
            *(bf16x8*)(Vt + (size_t)head * 65536 +
                       (size_t)(si0 / 8 + c) * 512 + (size_t)d * 8) = v;
        }
    }
}

// ---------------------------------------------------------------------------
// Kernel 2: fused attention. Block = (head, 128-row q-tile); wave owns 32
// q-rows. S^T computed via MFMA(K,Q) so P-writes are b64 (4 consecutive keys
// per lane). Q frags straight from global; ones-column frag synthesized in
// regs. XCD-affine block swizzle: a head's 8 q-tiles share one XCD's L2.
// T5: s_setprio(1) around both MFMA clusters (+4-7% on attn, m191 A/B —
// blocks here are NOT barrier-lockstep across the CU, the regime where
// setprio pays).
// ---------------------------------------------------------------------------
__global__ void __launch_bounds__(256, 4) k_attn(
    const bf16_t* __restrict__ Qh, const bf16_t* __restrict__ Kh,
    const bf16_t* __restrict__ Vg, bf16_t* __restrict__ Ctx)
{
    __shared__ bf16_t Ks[64 * 64];
    __shared__ bf16_t Vts[64 * 64];     // V^T tile (rows=d, cols=key), XOR-swizzled
    __shared__ bf16_t Pw[4][32 * 64];   // per-wave P [qrow][key], XOR-swizzled

    const int bid = blockIdx.x;
    const int head = (bid & 7) * 16 + ((bid >> 3) & 15);  // bid%8 = XCD (heuristic)
    const int qt = bid >> 7;
    const int t = threadIdx.x;
    const int wave = t >> 6, lane = t & 63;
    const int quad = lane >> 4, l16 = lane & 15;

    const bf16_t* Qg = Qh + (size_t)head * 65536 + (size_t)qt * 8192;
    const bf16_t* Kg = Kh + (size_t)head * 65536;
    const bf16_t* Vgh = Vg + (size_t)head * 65536;   // [sc][d][s7]

    // Q b-frags from global: lane l16 = q-row, 16B contiguous per lane
    bf16x8 qf[2][2];
    #pragma unroll
    for (int half = 0; half < 2; ++half)
        #pragma unroll
        for (int ks = 0; ks < 2; ++ks)
            qf[half][ks] = *(const bf16x8*)(
                Qg + (size_t)(wave * 32 + half * 16 + l16) * 64 + ks * 32 + quad * 8);

    // ones-column B-frag: column 64 of [V | 1 | 0] augmentation -> l16==0 lanes
    bf16x8 ones;
    #pragma unroll
    for (int e = 0; e < 8; ++e) ones[e] = (bf16_t)((l16 == 0) ? 1.0f : 0.0f);

    f32x4 vacc[2][5] = {};

    for (int kt = 0; kt < 16; ++kt) {
        __syncthreads();
        #pragma unroll
        for (int p = 0; p < 2; ++p) {
            const int rb = wave * 16 + p * 8;
            stage64(Kg + (size_t)(kt * 64 + rb) * 64, 64, Ks + rb * 64, lane);
            {   // V^T staging from [sc][d][s7]
                const int rr = lane >> 3, cl = lane & 7;
                const bf16_t* g = Vgh + (size_t)(kt * 8 + (cl ^ rr)) * 512
                                      + (size_t)(rb + rr) * 8;
                __builtin_amdgcn_global_load_lds(
                    (__attribute__((address_space(1))) const void*)g,
                    (__attribute__((address_space(3))) void*)(Vts + rb * 64), 16, 0, 0);
            }
        }
        __syncthreads();

        // S^T = K Q^T : D[key][qrow]; lane holds keys quad*4+rg (consecutive!)
        f32x4 s[2][4] = {};
        __builtin_amdgcn_s_setprio(1);
        #pragma unroll
        for (int ks = 0; ks < 2; ++ks) {
            #pragma unroll
            for (int j = 0; j < 4; ++j) {
                bf16x8 kf = *(const bf16x8*)tile_ptr(Ks, j * 16 + l16, ks * 4 + quad);
                s[0][j] = MFMA16(kf, qf[0][ks], s[0][j]);
                s[1][j] = MFMA16(kf, qf[1][ks], s[1][j]);
            }
        }
        __builtin_amdgcn_s_setprio(0);

        // P = exp2(S) -> Pw[qrow][key], 4 consecutive keys per lane = b64 write
        #pragma unroll
        for (int half = 0; half < 2; ++half) {
            const int row = half * 16 + l16;
            #pragma unroll
            for (int j = 0; j < 4; ++j) {
                bf16x4 pv;
                #pragma unroll
                for (int rg = 0; rg < 4; ++rg)
                    pv[rg] = (bf16_t)exp2f(s[half][j][rg]);
                const int chunk = j * 2 + (quad >> 1);
                *(bf16x4*)&Pw[wave][row * 64 + ((chunk ^ (row & 7)) << 3) + (quad & 1) * 4] = pv;
            }
        }
        asm volatile("s_waitcnt lgkmcnt(0)" ::: "memory");  // wave-local write->read

        // ctx_aug += P @ [V | 1]
        __builtin_amdgcn_s_setprio(1);
        #pragma unroll
        for (int ks = 0; ks < 2; ++ks) {
            bf16x8 pf0 = *(const bf16x8*)tile_ptr(Pw[wave], l16, ks * 4 + quad);
            bf16x8 pf1 = *(const bf16x8*)tile_ptr(Pw[wave], 16 + l16, ks * 4 + quad);
            #pragma unroll
            for (int n = 0; n < 4; ++n) {
                bf16x8 vf = *(const bf16x8*)tile_ptr(Vts, n * 16 + l16, ks * 4 + quad);
                vacc[0][n] = MFMA16(pf0, vf, vacc[0][n]);
                vacc[1][n] = MFMA16(pf1, vf, vacc[1][n]);
            }
            vacc[0][4] = MFMA16(pf0, ones, vacc[0][4]);
            vacc[1][4] = MFMA16(pf1, ones, vacc[1][4]);
        }
        __builtin_amdgcn_s_setprio(0);
    }

    const int bi = head >> 4, h = head & 15;
    #pragma unroll
    for (int half = 0; half < 2; ++half) {
        #pragma unroll
        for (int rg = 0; rg < 4; ++rg) {
            const float l = __shfl(vacc[half][4][rg], lane & 48, 64);
            const float inv = 1.0f / l;
            const int si = qt * 128 + wave * 32 + half * 16 + quad * 4 + rg;
            #pragma unroll
            for (int n = 0; n < 4; ++n)
                Ctx[((size_t)si * 8 + bi) * 1024 + h * 64 + n * 16 + l16] =
                    (bf16_t)(vacc[half][n][rg] * inv);
        }
    }
}

// ---------------------------------------------------------------------------
// Kernel 3: output projection (m97 structure).
// ---------------------------------------------------------------------------
__global__ void __launch_bounds__(256) k_out(
    const bf16_t* __restrict__ A, const bf16_t* __restrict__ W,
    const float* __restrict__ bias, float* __restrict__ out)
{
    __shared__ bf16_t As[128 * 64];
    __shared__ bf16_t Bs[128 * 64];
    const int m0 = blockIdx.x * 128;
    const int n0 = blockIdx.y * 128;
    const int t = threadIdx.x;
    const int wave = t >> 6, lane = t & 63;
    const int quad = lane >> 4, l16 = lane & 15;
    const int wm = (wave & 1) * 64, wn = (wave >> 1) * 64;

    f32x4 acc[4][4] = {};

    for (int k0 = 0; k0 < 1024; k0 += 64) {
        __syncthreads();
        #pragma unroll
        for (int p = 0; p < 4; ++p) {
            const int rb = wave * 32 + p * 8;
            stage64(A + (size_t)(m0 + rb) * 1024 + k0, 1024, As + rb * 64, lane);
            stage64(W + (size_t)(n0 + rb) * 1024 + k0, 1024, Bs + rb * 64, lane);
        }
        __syncthreads();
        #pragma unroll
        for (int ks = 0; ks < 2; ++ks) {
            bf16x8 af[4], bf[4];
            #pragma unroll
            for (int i = 0; i < 4; ++i)
                af[i] = *(const bf16x8*)tile_ptr(As, wm + i * 16 + l16, ks * 4 + quad);
            #pragma unroll
            for (int j = 0; j < 4; ++j)
                bf[j] = *(const bf16x8*)tile_ptr(Bs, wn + j * 16 + l16, ks * 4 + quad);
            #pragma unroll
            for (int i = 0; i < 4; ++i)
                #pragma unroll
                for (int j = 0; j < 4; ++j)
                    acc[i][j] = MFMA16(af[i], bf[j], acc[i][j]);
        }
    }

    #pragma unroll
    for (int j = 0; j < 4; ++j) {
        const int n = n0 + wn + j * 16 + l16;
        const float bv = bias[n];
        #pragma unroll
        for (int i = 0; i < 4; ++i) {
            #pragma unroll
            for (int rg = 0; rg < 4; ++rg) {
                const int m = m0 + wm + i * 16 + quad * 4 + rg;
                out[(size_t)m * 1024 + n] = acc[i][j][rg] + bv;
            }
        }
    }
}

// ---------------------------------------------------------------------------
extern "C" void kernel_launch(void* const* d_in, const int* in_sizes, int n_in,
                              void* d_out, int out_size, void* d_ws, size_t ws_size,
                              hipStream_t stream)
{
    const float* query = (const float*)d_in[0];
    const float* in_w  = (const float*)d_in[3];
    const float* in_b  = (const float*)d_in[4];
    const float* out_w = (const float*)d_in[5];
    const float* out_b = (const float*)d_in[6];
    float* out = (float*)d_out;

    bf16_t* Wi  = (bf16_t*)d_ws;                 //  3,145,728
    bf16_t* Wo  = Wi + (size_t)3145728;          //  1,048,576
    bf16_t* Qh  = Wo + (size_t)1048576;          //  8,388,608
    bf16_t* Kh  = Qh + (size_t)8388608;          //  8,388,608
    bf16_t* Vt  = Kh + (size_t)8388608;          //  8,388,608
    bf16_t* Aq  = Vt + (size_t)8388608;          //  8,388,608 (Ctx after k_qkv)
    bf16_t* Ctx = Aq;

    k_cvt<<<dim3(6144), 256, 0, stream>>>(query, in_w, out_w, Aq, Wi, Wo);
    k_qkv<<<dim3(64, 24), 256, 0, stream>>>(Aq, Wi, in_b, Qh, Kh, Vt);
    k_attn<<<dim3(1024), 256, 0, stream>>>(Qh, Kh, Vt, Ctx);
    k_out<<<dim3(64, 8), 256, 0, stream>>>(Ctx, Wo, out_b, out);
}